// Round 5
// baseline (936.828 us; speedup 1.0000x reference)
//
#include <hip/hip_runtime.h>
#include <hip/hip_bf16.h>

#define N_NODES 100000
#define N_EDGES 3200000
#define N_GRAPHS 256
#define SCAN_NB 98   // ceil(100000/1024)

typedef __hip_bfloat16 bf16;
using f32x4  = __attribute__((ext_vector_type(4))) float;
using short8 = __attribute__((ext_vector_type(8))) short;

// ------------------------------------------------------------------
// CSR build, single atomic pass
// ------------------------------------------------------------------
__global__ void rank_kernel(const int* __restrict__ dst, int* __restrict__ cnt,
                            unsigned short* __restrict__ rank) {
    int e = blockIdx.x * blockDim.x + threadIdx.x;
    if (e < N_EDGES) rank[e] = (unsigned short)atomicAdd(&cnt[dst[e]], 1);
}

__global__ __launch_bounds__(1024) void scan_blocks_kernel(const int* __restrict__ cnt,
                                                           int* __restrict__ excl,
                                                           int* __restrict__ partial) {
    __shared__ int buf[1024];
    int tid = threadIdx.x;
    int i = blockIdx.x * 1024 + tid;
    int v = (i < N_NODES) ? cnt[i] : 0;
    buf[tid] = v;
    __syncthreads();
    for (int off = 1; off < 1024; off <<= 1) {
        int t = (tid >= off) ? buf[tid - off] : 0;
        __syncthreads();
        buf[tid] += t;
        __syncthreads();
    }
    if (i < N_NODES) excl[i] = buf[tid] - v;
    if (tid == 1023) partial[blockIdx.x] = buf[1023];
}

__global__ __launch_bounds__(128) void scan_partial_kernel(int* __restrict__ partial) {
    __shared__ int sp[128];
    int tid = threadIdx.x;
    int v = (tid < SCAN_NB) ? partial[tid] : 0;
    sp[tid] = v;
    __syncthreads();
    for (int off = 1; off < 128; off <<= 1) {
        int t = (tid >= off) ? sp[tid - off] : 0;
        __syncthreads();
        sp[tid] += t;
        __syncthreads();
    }
    if (tid <= SCAN_NB) partial[tid] = sp[tid] - v;   // exclusive
}

__global__ void scan_add_kernel(const int* __restrict__ excl, const int* __restrict__ partial,
                                const int* __restrict__ cnt, int* __restrict__ rowptr,
                                float* __restrict__ invdeg) {
    int i = blockIdx.x * blockDim.x + threadIdx.x;
    if (i < N_NODES) {
        rowptr[i] = excl[i] + partial[i >> 10];
        invdeg[i] = 1.0f / fmaxf((float)cnt[i], 1.0f);
    } else if (i == N_NODES) {
        rowptr[N_NODES] = partial[SCAN_NB];
    }
}

__global__ void place2_kernel(const int* __restrict__ src, const int* __restrict__ dst,
                              const unsigned short* __restrict__ rank,
                              const int* __restrict__ rowptr, int* __restrict__ cols) {
    int e = blockIdx.x * blockDim.x + threadIdx.x;
    if (e < N_EDGES) cols[rowptr[dst[e]] + (int)rank[e]] = src[e];
}

// ------------------------------------------------------------------
// per-node ascending sort of neighbor lists (128-wide bitonic chunks).
// One 64-thread wave per node, wave-synchronous LDS (no __syncthreads:
// 64 threads = one wave, DS ops are in-order per wave).
// Sum order is irrelevant; sorting improves gather locality.
// ------------------------------------------------------------------
__global__ __launch_bounds__(256) void sortcols_kernel(const int* __restrict__ rowptr,
                                                       int* __restrict__ cols) {
    __shared__ int keys[4][128];
    int node = blockIdx.x * 4 + (threadIdx.x >> 6);   // N_NODES % 4 == 0
    int t = threadIdx.x & 63;
    int* k = keys[threadIdx.x >> 6];
    int s = rowptr[node], e = rowptr[node + 1];
    for (int base = s; base < e; base += 128) {
        int m = min(128, e - base);
#pragma unroll
        for (int i = t; i < 128; i += 64) k[i] = (i < m) ? cols[base + i] : 0x7fffffff;
        for (int kk = 2; kk <= 128; kk <<= 1) {
            for (int jj = kk >> 1; jj >= 1; jj >>= 1) {
#pragma unroll
                for (int i = t; i < 128; i += 64) {
                    int p = i ^ jj;
                    if (p > i) {
                        bool up = ((i & kk) == 0);
                        int a = k[i], b = k[p];
                        if ((a > b) == up) { k[i] = b; k[p] = a; }
                    }
                }
            }
        }
        for (int i = t; i < m; i += 64) cols[base + i] = k[i];
    }
}

// ------------------------------------------------------------------
// x fp32 [N][50] -> bf16 [N][64] zero-padded
// ------------------------------------------------------------------
__global__ void xprep_kernel(const float* __restrict__ x, bf16* __restrict__ xb) {
    int t = blockIdx.x * blockDim.x + threadIdx.x;
    if (t >= N_NODES * 64) return;
    int n = t >> 6, f = t & 63;
    xb[t] = __float2bfloat16(f < 50 ? x[(size_t)n * 50 + f] : 0.f);
}

// ------------------------------------------------------------------
// merged weight prep: all six fp32 weights -> bf16 (K zero-padded)
// ------------------------------------------------------------------
__device__ __forceinline__ void wcvt(const float* __restrict__ s, bf16* __restrict__ d,
                                     int Din, int Kp, int lt) {
    int o = lt / Kp, kk = lt % Kp;
    d[lt] = __float2bfloat16(kk < Din ? s[(size_t)o * Din + kk] : 0.f);
}

__global__ void wprep_all_kernel(const float* w1l, const float* w1r,
                                 const float* w2l, const float* w2r,
                                 const float* w3l, const float* w3r,
                                 bf16* w1l_b, bf16* w1r_b, bf16* w2l_b, bf16* w2r_b,
                                 bf16* w3l_b, bf16* w3r_b) {
    int t = blockIdx.x * blockDim.x + threadIdx.x;
    if      (t < 8192)   wcvt(w1l, w1l_b, 50, 64, t);
    else if (t < 16384)  wcvt(w1r, w1r_b, 50, 64, t - 8192);
    else if (t < 49152)  wcvt(w2l, w2l_b, 128, 128, t - 16384);
    else if (t < 81920)  wcvt(w2r, w2r_b, 128, 128, t - 49152);
    else if (t < 212992) wcvt(w3l, w3l_b, 256, 256, t - 81920);
    else if (t < 344064) wcvt(w3r, w3r_b, 256, 256, t - 212992);
}

// ------------------------------------------------------------------
// vectorized gather aggregation (bf16, D in {64,128,256}), 4-edge unroll
// ------------------------------------------------------------------
template <int D>
__global__ void aggv_kernel(const bf16* __restrict__ h, const int* __restrict__ rowptr,
                            const int* __restrict__ cols, const float* __restrict__ invdeg,
                            bf16* __restrict__ AG) {
    constexpr int L = D / 8;
    int n = blockIdx.x * (256 / L) + threadIdx.x / L;
    int lane = threadIdx.x % L;
    if (n >= N_NODES) return;
    int s = rowptr[n], e = rowptr[n + 1];
    float acc[8] = {};
    auto accum = [&](uint4 v) {
        const unsigned short* u = (const unsigned short*)&v;
#pragma unroll
        for (int i = 0; i < 8; ++i) {
            union { unsigned int ui; float f; } cv;
            cv.ui = ((unsigned int)u[i]) << 16;
            acc[i] += cv.f;
        }
    };
    int j = s;
    for (; j + 4 <= e; j += 4) {
        int c0 = cols[j], c1 = cols[j + 1], c2 = cols[j + 2], c3 = cols[j + 3];
        uint4 v0 = *(const uint4*)&h[(size_t)c0 * D + lane * 8];
        uint4 v1 = *(const uint4*)&h[(size_t)c1 * D + lane * 8];
        uint4 v2 = *(const uint4*)&h[(size_t)c2 * D + lane * 8];
        uint4 v3 = *(const uint4*)&h[(size_t)c3 * D + lane * 8];
        accum(v0); accum(v1); accum(v2); accum(v3);
    }
    for (; j < e; ++j) accum(*(const uint4*)&h[(size_t)cols[j] * D + lane * 8]);
    float inv = invdeg[n];
    union { uint4 u; bf16 h8[8]; } o;
#pragma unroll
    for (int i = 0; i < 8; ++i) o.h8[i] = __float2bfloat16(acc[i] * inv);
    *(uint4*)&AG[(size_t)n * D + lane * 8] = o.u;
}

// ------------------------------------------------------------------
// m97-style MFMA GEMM: global_load_lds(16B), linear LDS, 2-barrier loop.
// C = act( [A1|A2] @ [B1|B2]^T + bias ); all operands ld == Kh, bf16.
// ACT: 0 = leaky_relu(0.01), 1 = relu. POOL=1: fused segmented pooling.
// ------------------------------------------------------------------
template <int ACT, int POOL>
__global__ __launch_bounds__(256) void glds_gemm(
        const bf16* __restrict__ A1, const bf16* __restrict__ A2, int Kh,
        const bf16* __restrict__ B1, const bf16* __restrict__ B2,
        const float* __restrict__ bias, bf16* __restrict__ out,
        int M, int Dout,
        const int* __restrict__ batch, float* __restrict__ pooled) {
    __shared__ alignas(16) bf16 As[128][32];
    __shared__ alignas(16) bf16 Bs[128][32];
    __shared__ int sbatch[128];

    const int tid = threadIdx.x;
    const int n0 = blockIdx.y * 128;
    const int o0 = blockIdx.x * 128;

    if (POOL && tid < 128) {
        int n = n0 + tid;
        sbatch[tid] = (n < M) ? batch[n] : -1;
    }

    const int lane = tid & 63;
    const int w = tid >> 6;
    const int wr = w >> 1, wc = w & 1;
    const int lr = lane & 15, hi = lane >> 4;
    const int l4 = lane >> 2;          // 0..15: row within 16-row chunk
    const int kc8 = (lane & 3) * 8;    // 0,8,16,24

    f32x4 acc[4][4] = {};

    const int KT = 2 * Kh;
    for (int k0 = 0; k0 < KT; k0 += 32) {
        const bf16* Ap;
        const bf16* Bp;
        int kk;
        if (k0 < Kh) { Ap = A1; Bp = B1; kk = k0; }
        else         { Ap = A2; Bp = B2; kk = k0 - Kh; }
#pragma unroll
        for (int c = 0; c < 2; ++c) {
            int rl = w * 32 + c * 16 + l4;  // tile row 0..127
            size_t ga = (size_t)min(n0 + rl, M - 1) * (size_t)Kh + kk + kc8;
            __builtin_amdgcn_global_load_lds(
                (const __attribute__((address_space(1))) void*)(Ap + ga),
                (__attribute__((address_space(3))) void*)&As[w * 32 + c * 16][0], 16, 0, 0);
            size_t gb = (size_t)(o0 + rl) * (size_t)Kh + kk + kc8;
            __builtin_amdgcn_global_load_lds(
                (const __attribute__((address_space(1))) void*)(Bp + gb),
                (__attribute__((address_space(3))) void*)&Bs[w * 32 + c * 16][0], 16, 0, 0);
        }
        __syncthreads();   // drains vmcnt(0): DMA landed

        short8 af[4], bfr[4];
#pragma unroll
        for (int m = 0; m < 4; ++m)
            af[m] = *(const short8*)&As[wr * 64 + m * 16 + lr][hi * 8];
#pragma unroll
        for (int n = 0; n < 4; ++n)
            bfr[n] = *(const short8*)&Bs[wc * 64 + n * 16 + lr][hi * 8];
#pragma unroll
        for (int m = 0; m < 4; ++m)
#pragma unroll
            for (int n = 0; n < 4; ++n)
                acc[m][n] = __builtin_amdgcn_mfma_f32_16x16x32_bf16(af[m], bfr[n], acc[m][n], 0, 0, 0);
        __syncthreads();   // all waves done reading before next DMA
    }

    float bias_v[4];
#pragma unroll
    for (int n = 0; n < 4; ++n) bias_v[n] = bias[o0 + wc * 64 + n * 16 + lr];

    if (!POOL) {
#pragma unroll
        for (int m = 0; m < 4; ++m) {
#pragma unroll
            for (int j = 0; j < 4; ++j) {
                int row = n0 + wr * 64 + m * 16 + hi * 4 + j;
                if (row < M) {
#pragma unroll
                    for (int n = 0; n < 4; ++n) {
                        float s = acc[m][n][j] + bias_v[n];
                        if (ACT == 0) s = (s >= 0.f) ? s : 0.01f * s;
                        else          s = fmaxf(s, 0.f);
                        out[(size_t)row * Dout + o0 + wc * 64 + n * 16 + lr] = __float2bfloat16(s);
                    }
                }
            }
        }
    } else {
        int lastv = min(127, M - 1 - n0);
        int gmin = sbatch[0], gmax = sbatch[lastv];
        for (int g = gmin; g <= gmax; ++g) {
            float s[4] = {0.f, 0.f, 0.f, 0.f};
#pragma unroll
            for (int m = 0; m < 4; ++m) {
#pragma unroll
                for (int j = 0; j < 4; ++j) {
                    int rl = wr * 64 + m * 16 + hi * 4 + j;
                    if (sbatch[rl] == g) {
#pragma unroll
                        for (int n = 0; n < 4; ++n)
                            s[n] += fmaxf(acc[m][n][j] + bias_v[n], 0.f);
                    }
                }
            }
#pragma unroll
            for (int n = 0; n < 4; ++n) {
                float v = s[n];
                v += __shfl_xor(v, 16, 64);
                v += __shfl_xor(v, 32, 64);
                if (hi == 0)
                    atomicAdd(&pooled[(size_t)g * 512 + o0 + wc * 64 + n * 16 + lr], v);
            }
        }
    }
}

// ------------------------------------------------------------------
// graph boundaries + pool finalize + MLP head
// ------------------------------------------------------------------
__global__ void bounds_kernel(const int* __restrict__ batch, int* __restrict__ gstart) {
    int g = blockIdx.x * blockDim.x + threadIdx.x;
    if (g > N_GRAPHS) return;
    int lo = 0, hi = N_NODES;
    while (lo < hi) {
        int mid = (lo + hi) >> 1;
        if (batch[mid] < g) lo = mid + 1;
        else hi = mid;
    }
    gstart[g] = lo;
}

__global__ void pool_finalize(float* __restrict__ pooled, const int* __restrict__ gstart) {
    int g = blockIdx.x;
    int f = threadIdx.x;
    float cnt = fmaxf((float)(gstart[g + 1] - gstart[g]), 1.0f);
    pooled[(size_t)g * 512 + f] /= cnt;
}

template <int ACT>  // 0 = none, 1 = relu
__global__ void mlp_kernel(const float* __restrict__ in, const float* __restrict__ w,
                           const float* __restrict__ b, float* __restrict__ out,
                           int M, int K, int O) {
    int t = blockIdx.x * blockDim.x + threadIdx.x;
    if (t >= M * O) return;
    int m = t / O, o = t % O;
    const float* ip = in + (size_t)m * K;
    const float* wp = w + (size_t)o * K;
    float s = 0.f;
    for (int k = 0; k < K; ++k) s += ip[k] * wp[k];
    s += b[o];
    if (ACT) s = fmaxf(s, 0.f);
    out[(size_t)m * O + o] = s;
}

// ------------------------------------------------------------------
extern "C" void kernel_launch(void* const* d_in, const int* in_sizes, int n_in,
                              void* d_out, int out_size, void* d_ws, size_t ws_size,
                              hipStream_t stream) {
    const float* x     = (const float*)d_in[0];
    const int*   ei    = (const int*)d_in[1];
    const int*   batch = (const int*)d_in[2];
    const float* w1l = (const float*)d_in[3];
    const float* b1  = (const float*)d_in[4];
    const float* w1r = (const float*)d_in[5];
    const float* w2l = (const float*)d_in[6];
    const float* b2  = (const float*)d_in[7];
    const float* w2r = (const float*)d_in[8];
    const float* w3l = (const float*)d_in[9];
    const float* b3  = (const float*)d_in[10];
    const float* w3r = (const float*)d_in[11];
    const float* fc1_w = (const float*)d_in[12];
    const float* fc1_b = (const float*)d_in[13];
    const float* fc2_w = (const float*)d_in[14];
    const float* fc2_b = (const float*)d_in[15];
    const float* cls_w = (const float*)d_in[16];
    const float* cls_b = (const float*)d_in[17];
    float* out = (float*)d_out;

    const int* src = ei;
    const int* dst = ei + N_EDGES;

    // ---- workspace layout ----
    char* wsp = (char*)d_ws;
    size_t used = 0;
    auto alloc = [&](size_t bytes) {
        char* p = wsp + used;
        used += (bytes + 255) & ~(size_t)255;
        return p;
    };
    int*   cnt    = (int*)alloc((size_t)N_NODES * 4);
    int*   rowptr = (int*)alloc((size_t)(N_NODES + 1) * 4);
    int*   excl   = (int*)alloc((size_t)N_NODES * 4);
    int*   partial= (int*)alloc((size_t)(SCAN_NB + 1) * 4);
    int*   cols   = (int*)alloc((size_t)N_EDGES * 4);
    unsigned short* rank = (unsigned short*)alloc((size_t)N_EDGES * 2);
    float* invdeg = (float*)alloc((size_t)N_NODES * 4);
    int*   gstart = (int*)alloc((size_t)(N_GRAPHS + 1) * 4);
    bf16*  xb     = (bf16*)alloc((size_t)N_NODES * 64 * 2);
    char*  R      = alloc((size_t)N_NODES * 256 * 2);           // overlay
    bf16*  AG     = (bf16*)R;                                   // per-layer agg
    bf16*  h1     = (bf16*)(R + (size_t)N_NODES * 128 * 2);     // dead after L2 gemm
    bf16*  h2     = (bf16*)alloc((size_t)N_NODES * 256 * 2);
    bf16*  w1l_b  = (bf16*)alloc(128 * 64 * 2);
    bf16*  w1r_b  = (bf16*)alloc(128 * 64 * 2);
    bf16*  w2l_b  = (bf16*)alloc(256 * 128 * 2);
    bf16*  w2r_b  = (bf16*)alloc(256 * 128 * 2);
    bf16*  w3l_b  = (bf16*)alloc(512 * 256 * 2);
    bf16*  w3r_b  = (bf16*)alloc(512 * 256 * 2);
    float* pooled = (float*)alloc((size_t)N_GRAPHS * 512 * 4);
    float* z1     = (float*)alloc((size_t)N_GRAPHS * 256 * 4);
    float* z2     = (float*)alloc((size_t)N_GRAPHS * 128 * 4);

    if (ws_size < used) return;

    // ---- CSR build (one atomic pass) + sort neighbor lists ----
    hipMemsetAsync(cnt, 0, (size_t)N_NODES * 4, stream);
    rank_kernel<<<(N_EDGES + 255) / 256, 256, 0, stream>>>(dst, cnt, rank);
    scan_blocks_kernel<<<SCAN_NB, 1024, 0, stream>>>(cnt, excl, partial);
    scan_partial_kernel<<<1, 128, 0, stream>>>(partial);
    scan_add_kernel<<<(N_NODES + 256) / 256, 256, 0, stream>>>(excl, partial, cnt, rowptr, invdeg);
    place2_kernel<<<(N_EDGES + 255) / 256, 256, 0, stream>>>(src, dst, rank, rowptr, cols);
    sortcols_kernel<<<N_NODES / 4, 256, 0, stream>>>(rowptr, cols);
    bounds_kernel<<<2, 160, 0, stream>>>(batch, gstart);

    // ---- input/weight prep ----
    xprep_kernel<<<(N_NODES * 64 + 255) / 256, 256, 0, stream>>>(x, xb);
    wprep_all_kernel<<<(344064 + 255) / 256, 256, 0, stream>>>(
        w1l, w1r, w2l, w2r, w3l, w3r, w1l_b, w1r_b, w2l_b, w2r_b, w3l_b, w3r_b);

    const int MB = (N_NODES + 127) / 128;  // 782

    // ---- layer 1: 50(pad 64) -> 128, leaky_relu ----
    aggv_kernel<64><<<(N_NODES * 8 + 255) / 256, 256, 0, stream>>>(xb, rowptr, cols, invdeg, AG);
    glds_gemm<0, 0><<<dim3(1, MB), 256, 0, stream>>>(
        AG, xb, 64, w1l_b, w1r_b, b1, h1, N_NODES, 128, nullptr, nullptr);

    // ---- layer 2: 128 -> 256, relu ----
    aggv_kernel<128><<<(N_NODES * 16 + 255) / 256, 256, 0, stream>>>(h1, rowptr, cols, invdeg, AG);
    glds_gemm<1, 0><<<dim3(2, MB), 256, 0, stream>>>(
        AG, h1, 128, w2l_b, w2r_b, b2, h2, N_NODES, 256, nullptr, nullptr);

    // ---- layer 3: 256 -> 512, relu, fused pooled sum ----
    aggv_kernel<256><<<(N_NODES * 32 + 255) / 256, 256, 0, stream>>>(h2, rowptr, cols, invdeg, AG);
    hipMemsetAsync(pooled, 0, (size_t)N_GRAPHS * 512 * 4, stream);
    glds_gemm<1, 1><<<dim3(4, MB), 256, 0, stream>>>(
        AG, h2, 256, w3l_b, w3r_b, b3, nullptr, N_NODES, 512, batch, pooled);
    pool_finalize<<<N_GRAPHS, 512, 0, stream>>>(pooled, gstart);

    // ---- MLP head ----
    mlp_kernel<1><<<(N_GRAPHS * 256 + 255) / 256, 256, 0, stream>>>(
        pooled, fc1_w, fc1_b, z1, N_GRAPHS, 512, 256);
    mlp_kernel<1><<<(N_GRAPHS * 128 + 255) / 256, 256, 0, stream>>>(
        z1, fc2_w, fc2_b, z2, N_GRAPHS, 256, 128);
    mlp_kernel<0><<<(N_GRAPHS * 15 + 255) / 256, 256, 0, stream>>>(
        z2, cls_w, cls_b, out, N_GRAPHS, 128, 15);
}

// Round 7
// 703.868 us; speedup vs baseline: 1.3310x; 1.3310x over previous
//
#include <hip/hip_runtime.h>
#include <hip/hip_bf16.h>

#define N_NODES 100000
#define N_EDGES 3200000
#define N_GRAPHS 256
#define SCAN_NB 98   // ceil(100000/1024)

typedef __hip_bfloat16 bf16;
using f32x4  = __attribute__((ext_vector_type(4))) float;
using f32x2  = __attribute__((ext_vector_type(2))) float;
using short8 = __attribute__((ext_vector_type(8))) short;

// ------------------------------------------------------------------
// CSR build, single atomic pass
// ------------------------------------------------------------------
__global__ void rank_kernel(const int* __restrict__ dst, int* __restrict__ cnt,
                            unsigned short* __restrict__ rank) {
    int e = blockIdx.x * blockDim.x + threadIdx.x;
    if (e < N_EDGES) rank[e] = (unsigned short)atomicAdd(&cnt[dst[e]], 1);
}

__global__ __launch_bounds__(1024) void scan_blocks_kernel(const int* __restrict__ cnt,
                                                           int* __restrict__ excl,
                                                           int* __restrict__ partial) {
    __shared__ int buf[1024];
    int tid = threadIdx.x;
    int i = blockIdx.x * 1024 + tid;
    int v = (i < N_NODES) ? cnt[i] : 0;
    buf[tid] = v;
    __syncthreads();
    for (int off = 1; off < 1024; off <<= 1) {
        int t = (tid >= off) ? buf[tid - off] : 0;
        __syncthreads();
        buf[tid] += t;
        __syncthreads();
    }
    if (i < N_NODES) excl[i] = buf[tid] - v;
    if (tid == 1023) partial[blockIdx.x] = buf[1023];
}

__global__ __launch_bounds__(128) void scan_partial_kernel(int* __restrict__ partial) {
    __shared__ int sp[128];
    int tid = threadIdx.x;
    int v = (tid < SCAN_NB) ? partial[tid] : 0;
    sp[tid] = v;
    __syncthreads();
    for (int off = 1; off < 128; off <<= 1) {
        int t = (tid >= off) ? sp[tid - off] : 0;
        __syncthreads();
        sp[tid] += t;
        __syncthreads();
    }
    if (tid <= SCAN_NB) partial[tid] = sp[tid] - v;   // exclusive
}

__global__ void scan_add_kernel(const int* __restrict__ excl, const int* __restrict__ partial,
                                const int* __restrict__ cnt, int* __restrict__ rowptr,
                                float* __restrict__ invdeg) {
    int i = blockIdx.x * blockDim.x + threadIdx.x;
    if (i < N_NODES) {
        rowptr[i] = excl[i] + partial[i >> 10];
        invdeg[i] = 1.0f / fmaxf((float)cnt[i], 1.0f);
    } else if (i == N_NODES) {
        rowptr[N_NODES] = partial[SCAN_NB];
    }
}

__global__ void place2_kernel(const int* __restrict__ src, const int* __restrict__ dst,
                              const unsigned short* __restrict__ rank,
                              const int* __restrict__ rowptr, int* __restrict__ cols) {
    int e = blockIdx.x * blockDim.x + threadIdx.x;
    if (e < N_EDGES) cols[rowptr[dst[e]] + (int)rank[e]] = src[e];
}

// ------------------------------------------------------------------
// x fp32 [N][50] -> bf16 [N][64] zero-padded
// ------------------------------------------------------------------
__global__ void xprep_kernel(const float* __restrict__ x, bf16* __restrict__ xb) {
    int t = blockIdx.x * blockDim.x + threadIdx.x;
    if (t >= N_NODES * 64) return;
    int n = t >> 6, f = t & 63;
    xb[t] = __float2bfloat16(f < 50 ? x[(size_t)n * 50 + f] : 0.f);
}

// ------------------------------------------------------------------
// merged weight prep: all six fp32 weights -> bf16 (K zero-padded)
// ------------------------------------------------------------------
__device__ __forceinline__ void wcvt(const float* __restrict__ s, bf16* __restrict__ d,
                                     int Din, int Kp, int lt) {
    int o = lt / Kp, kk = lt % Kp;
    d[lt] = __float2bfloat16(kk < Din ? s[(size_t)o * Din + kk] : 0.f);
}

__global__ void wprep_all_kernel(const float* w1l, const float* w1r,
                                 const float* w2l, const float* w2r,
                                 const float* w3l, const float* w3r,
                                 bf16* w1l_b, bf16* w1r_b, bf16* w2l_b, bf16* w2r_b,
                                 bf16* w3l_b, bf16* w3r_b) {
    int t = blockIdx.x * blockDim.x + threadIdx.x;
    if      (t < 8192)   wcvt(w1l, w1l_b, 50, 64, t);
    else if (t < 16384)  wcvt(w1r, w1r_b, 50, 64, t - 8192);
    else if (t < 49152)  wcvt(w2l, w2l_b, 128, 128, t - 16384);
    else if (t < 81920)  wcvt(w2r, w2r_b, 128, 128, t - 49152);
    else if (t < 212992) wcvt(w3l, w3l_b, 256, 256, t - 81920);
    else if (t < 344064) wcvt(w3r, w3r_b, 256, 256, t - 212992);
}

// ------------------------------------------------------------------
// bf16 gather aggregation (layer 1, D=64)
// ------------------------------------------------------------------
template <int D>
__global__ void aggv_kernel(const bf16* __restrict__ h, const int* __restrict__ rowptr,
                            const int* __restrict__ cols, const float* __restrict__ invdeg,
                            bf16* __restrict__ AG) {
    constexpr int L = D / 8;
    int n = blockIdx.x * (256 / L) + threadIdx.x / L;
    int lane = threadIdx.x % L;
    if (n >= N_NODES) return;
    int s = rowptr[n], e = rowptr[n + 1];
    float acc[8] = {};
    auto accum = [&](uint4 v) {
        const unsigned short* u = (const unsigned short*)&v;
#pragma unroll
        for (int i = 0; i < 8; ++i) {
            union { unsigned int ui; float f; } cv;
            cv.ui = ((unsigned int)u[i]) << 16;
            acc[i] += cv.f;
        }
    };
    int j = s;
    for (; j + 4 <= e; j += 4) {
        int c0 = cols[j], c1 = cols[j + 1], c2 = cols[j + 2], c3 = cols[j + 3];
        uint4 v0 = *(const uint4*)&h[(size_t)c0 * D + lane * 8];
        uint4 v1 = *(const uint4*)&h[(size_t)c1 * D + lane * 8];
        uint4 v2 = *(const uint4*)&h[(size_t)c2 * D + lane * 8];
        uint4 v3 = *(const uint4*)&h[(size_t)c3 * D + lane * 8];
        accum(v0); accum(v1); accum(v2); accum(v3);
    }
    for (; j < e; ++j) accum(*(const uint4*)&h[(size_t)cols[j] * D + lane * 8]);
    float inv = invdeg[n];
    union { uint4 u; bf16 h8[8]; } o;
#pragma unroll
    for (int i = 0; i < 8; ++i) o.h8[i] = __float2bfloat16(acc[i] * inv);
    *(uint4*)&AG[(size_t)n * D + lane * 8] = o.u;
}

// ------------------------------------------------------------------
// fp8-e4m3 gather aggregation (layers 2/3): half the gather bytes.
// Each lane handles 8 features = 8 bytes; fp32 accumulate; bf16 out.
// ------------------------------------------------------------------
template <int D>
__global__ void aggv8_kernel(const unsigned char* __restrict__ h8,
                             const int* __restrict__ rowptr,
                             const int* __restrict__ cols, const float* __restrict__ invdeg,
                             bf16* __restrict__ AG) {
    constexpr int L = D / 8;
    int n = blockIdx.x * (256 / L) + threadIdx.x / L;
    int lane = threadIdx.x % L;
    if (n >= N_NODES) return;
    int s = rowptr[n], e = rowptr[n + 1];
    float acc[8] = {};
    auto accum = [&](uint2 v) {
        f32x2 a0 = __builtin_amdgcn_cvt_pk_f32_fp8(v.x, false);
        f32x2 a1 = __builtin_amdgcn_cvt_pk_f32_fp8(v.x, true);
        f32x2 a2 = __builtin_amdgcn_cvt_pk_f32_fp8(v.y, false);
        f32x2 a3 = __builtin_amdgcn_cvt_pk_f32_fp8(v.y, true);
        acc[0] += a0[0]; acc[1] += a0[1]; acc[2] += a1[0]; acc[3] += a1[1];
        acc[4] += a2[0]; acc[5] += a2[1]; acc[6] += a3[0]; acc[7] += a3[1];
    };
    int j = s;
    for (; j + 8 <= e; j += 8) {
        uint2 v[8];
#pragma unroll
        for (int q = 0; q < 8; ++q)
            v[q] = *(const uint2*)&h8[(size_t)cols[j + q] * D + lane * 8];
#pragma unroll
        for (int q = 0; q < 8; ++q) accum(v[q]);
    }
    for (; j < e; ++j) accum(*(const uint2*)&h8[(size_t)cols[j] * D + lane * 8]);
    float inv = invdeg[n];
    union { uint4 u; bf16 hb[8]; } o;
#pragma unroll
    for (int i = 0; i < 8; ++i) o.hb[i] = __float2bfloat16(acc[i] * inv);
    *(uint4*)&AG[(size_t)n * D + lane * 8] = o.u;
}

// ------------------------------------------------------------------
// m97-style MFMA GEMM: global_load_lds(16B), linear LDS, 2-barrier loop.
// C = act( [A1|A2] @ [B1|B2]^T + bias ); all operands ld == Kh, bf16.
// ACT: 0 = leaky_relu(0.01), 1 = relu. POOL=1: fused segmented pooling.
// OUT8=1: additionally write fp8-e4m3 shadow copy (gather payload).
// ------------------------------------------------------------------
template <int ACT, int POOL, int OUT8>
__global__ __launch_bounds__(256) void glds_gemm(
        const bf16* __restrict__ A1, const bf16* __restrict__ A2, int Kh,
        const bf16* __restrict__ B1, const bf16* __restrict__ B2,
        const float* __restrict__ bias, bf16* __restrict__ out,
        unsigned char* __restrict__ out8,
        int M, int Dout,
        const int* __restrict__ batch, float* __restrict__ pooled) {
    __shared__ alignas(16) bf16 As[128][32];
    __shared__ alignas(16) bf16 Bs[128][32];
    __shared__ int sbatch[128];

    const int tid = threadIdx.x;
    const int n0 = blockIdx.y * 128;
    const int o0 = blockIdx.x * 128;

    if (POOL && tid < 128) {
        int n = n0 + tid;
        sbatch[tid] = (n < M) ? batch[n] : -1;
    }

    const int lane = tid & 63;
    const int w = tid >> 6;
    const int wr = w >> 1, wc = w & 1;
    const int lr = lane & 15, hi = lane >> 4;
    const int l4 = lane >> 2;          // 0..15: row within 16-row chunk
    const int kc8 = (lane & 3) * 8;    // 0,8,16,24

    f32x4 acc[4][4] = {};

    const int KT = 2 * Kh;
    for (int k0 = 0; k0 < KT; k0 += 32) {
        const bf16* Ap;
        const bf16* Bp;
        int kk;
        if (k0 < Kh) { Ap = A1; Bp = B1; kk = k0; }
        else         { Ap = A2; Bp = B2; kk = k0 - Kh; }
#pragma unroll
        for (int c = 0; c < 2; ++c) {
            int rl = w * 32 + c * 16 + l4;  // tile row 0..127
            size_t ga = (size_t)min(n0 + rl, M - 1) * (size_t)Kh + kk + kc8;
            __builtin_amdgcn_global_load_lds(
                (const __attribute__((address_space(1))) void*)(Ap + ga),
                (__attribute__((address_space(3))) void*)&As[w * 32 + c * 16][0], 16, 0, 0);
            size_t gb = (size_t)(o0 + rl) * (size_t)Kh + kk + kc8;
            __builtin_amdgcn_global_load_lds(
                (const __attribute__((address_space(1))) void*)(Bp + gb),
                (__attribute__((address_space(3))) void*)&Bs[w * 32 + c * 16][0], 16, 0, 0);
        }
        __syncthreads();   // drains vmcnt(0): DMA landed

        short8 af[4], bfr[4];
#pragma unroll
        for (int m = 0; m < 4; ++m)
            af[m] = *(const short8*)&As[wr * 64 + m * 16 + lr][hi * 8];
#pragma unroll
        for (int n = 0; n < 4; ++n)
            bfr[n] = *(const short8*)&Bs[wc * 64 + n * 16 + lr][hi * 8];
#pragma unroll
        for (int m = 0; m < 4; ++m)
#pragma unroll
            for (int n = 0; n < 4; ++n)
                acc[m][n] = __builtin_amdgcn_mfma_f32_16x16x32_bf16(af[m], bfr[n], acc[m][n], 0, 0, 0);
        __syncthreads();   // all waves done reading before next DMA
    }

    float bias_v[4];
#pragma unroll
    for (int n = 0; n < 4; ++n) bias_v[n] = bias[o0 + wc * 64 + n * 16 + lr];

    if (!POOL) {
#pragma unroll
        for (int m = 0; m < 4; ++m) {
#pragma unroll
            for (int j = 0; j < 4; ++j) {
                int row = n0 + wr * 64 + m * 16 + hi * 4 + j;
                if (row < M) {
#pragma unroll
                    for (int n = 0; n < 4; ++n) {
                        int col = o0 + wc * 64 + n * 16 + lr;
                        float s = acc[m][n][j] + bias_v[n];
                        if (ACT == 0) s = (s >= 0.f) ? s : 0.01f * s;
                        else          s = fmaxf(s, 0.f);
                        out[(size_t)row * Dout + col] = __float2bfloat16(s);
                        if (OUT8) {
                            int p = __builtin_amdgcn_cvt_pk_fp8_f32(s, s, 0, false);
                            out8[(size_t)row * Dout + col] = (unsigned char)(p & 0xff);
                        }
                    }
                }
            }
        }
    } else {
        int lastv = min(127, M - 1 - n0);
        int gmin = sbatch[0], gmax = sbatch[lastv];
        for (int g = gmin; g <= gmax; ++g) {
            float s[4] = {0.f, 0.f, 0.f, 0.f};
#pragma unroll
            for (int m = 0; m < 4; ++m) {
#pragma unroll
                for (int j = 0; j < 4; ++j) {
                    int rl = wr * 64 + m * 16 + hi * 4 + j;
                    if (sbatch[rl] == g) {
#pragma unroll
                        for (int n = 0; n < 4; ++n)
                            s[n] += fmaxf(acc[m][n][j] + bias_v[n], 0.f);
                    }
                }
            }
#pragma unroll
            for (int n = 0; n < 4; ++n) {
                float v = s[n];
                v += __shfl_xor(v, 16, 64);
                v += __shfl_xor(v, 32, 64);
                if (hi == 0)
                    atomicAdd(&pooled[(size_t)g * 512 + o0 + wc * 64 + n * 16 + lr], v);
            }
        }
    }
}

// ------------------------------------------------------------------
// graph boundaries + pool finalize + MLP head
// ------------------------------------------------------------------
__global__ void bounds_kernel(const int* __restrict__ batch, int* __restrict__ gstart) {
    int g = blockIdx.x * blockDim.x + threadIdx.x;
    if (g > N_GRAPHS) return;
    int lo = 0, hi = N_NODES;
    while (lo < hi) {
        int mid = (lo + hi) >> 1;
        if (batch[mid] < g) lo = mid + 1;
        else hi = mid;
    }
    gstart[g] = lo;
}

__global__ void pool_finalize(float* __restrict__ pooled, const int* __restrict__ gstart) {
    int g = blockIdx.x;
    int f = threadIdx.x;
    float cnt = fmaxf((float)(gstart[g + 1] - gstart[g]), 1.0f);
    pooled[(size_t)g * 512 + f] /= cnt;
}

template <int ACT>  // 0 = none, 1 = relu
__global__ void mlp_kernel(const float* __restrict__ in, const float* __restrict__ w,
                           const float* __restrict__ b, float* __restrict__ out,
                           int M, int K, int O) {
    int t = blockIdx.x * blockDim.x + threadIdx.x;
    if (t >= M * O) return;
    int m = t / O, o = t % O;
    const float* ip = in + (size_t)m * K;
    const float* wp = w + (size_t)o * K;
    float s = 0.f;
    for (int k = 0; k < K; ++k) s += ip[k] * wp[k];
    s += b[o];
    if (ACT) s = fmaxf(s, 0.f);
    out[(size_t)m * O + o] = s;
}

// ------------------------------------------------------------------
extern "C" void kernel_launch(void* const* d_in, const int* in_sizes, int n_in,
                              void* d_out, int out_size, void* d_ws, size_t ws_size,
                              hipStream_t stream) {
    const float* x     = (const float*)d_in[0];
    const int*   ei    = (const int*)d_in[1];
    const int*   batch = (const int*)d_in[2];
    const float* w1l = (const float*)d_in[3];
    const float* b1  = (const float*)d_in[4];
    const float* w1r = (const float*)d_in[5];
    const float* w2l = (const float*)d_in[6];
    const float* b2  = (const float*)d_in[7];
    const float* w2r = (const float*)d_in[8];
    const float* w3l = (const float*)d_in[9];
    const float* b3  = (const float*)d_in[10];
    const float* w3r = (const float*)d_in[11];
    const float* fc1_w = (const float*)d_in[12];
    const float* fc1_b = (const float*)d_in[13];
    const float* fc2_w = (const float*)d_in[14];
    const float* fc2_b = (const float*)d_in[15];
    const float* cls_w = (const float*)d_in[16];
    const float* cls_b = (const float*)d_in[17];
    float* out = (float*)d_out;

    const int* src = ei;
    const int* dst = ei + N_EDGES;

    // ---- workspace layout ----
    char* wsp = (char*)d_ws;
    size_t used = 0;
    auto alloc = [&](size_t bytes) {
        char* p = wsp + used;
        used += (bytes + 255) & ~(size_t)255;
        return p;
    };
    int*   cnt    = (int*)alloc((size_t)N_NODES * 4);
    int*   rowptr = (int*)alloc((size_t)(N_NODES + 1) * 4);
    int*   excl   = (int*)alloc((size_t)N_NODES * 4);
    int*   partial= (int*)alloc((size_t)(SCAN_NB + 1) * 4);
    int*   cols   = (int*)alloc((size_t)N_EDGES * 4);
    unsigned short* rank = (unsigned short*)alloc((size_t)N_EDGES * 2);
    float* invdeg = (float*)alloc((size_t)N_NODES * 4);
    int*   gstart = (int*)alloc((size_t)(N_GRAPHS + 1) * 4);
    bf16*  xb     = (bf16*)alloc((size_t)N_NODES * 64 * 2);
    char*  R      = alloc((size_t)N_NODES * 256 * 2);           // overlay
    bf16*  AG     = (bf16*)R;                                   // per-layer agg
    bf16*  h1     = (bf16*)(R + (size_t)N_NODES * 128 * 2);     // dead after L2 gemm
    bf16*  h2     = (bf16*)alloc((size_t)N_NODES * 256 * 2);
    unsigned char* h1_8 = (unsigned char*)alloc((size_t)N_NODES * 128);
    unsigned char* h2_8 = (unsigned char*)alloc((size_t)N_NODES * 256);
    bf16*  w1l_b  = (bf16*)alloc(128 * 64 * 2);
    bf16*  w1r_b  = (bf16*)alloc(128 * 64 * 2);
    bf16*  w2l_b  = (bf16*)alloc(256 * 128 * 2);
    bf16*  w2r_b  = (bf16*)alloc(256 * 128 * 2);
    bf16*  w3l_b  = (bf16*)alloc(512 * 256 * 2);
    bf16*  w3r_b  = (bf16*)alloc(512 * 256 * 2);
    float* pooled = (float*)alloc((size_t)N_GRAPHS * 512 * 4);
    float* z1     = (float*)alloc((size_t)N_GRAPHS * 256 * 4);
    float* z2     = (float*)alloc((size_t)N_GRAPHS * 128 * 4);

    if (ws_size < used) return;

    // ---- CSR build (one atomic pass) ----
    hipMemsetAsync(cnt, 0, (size_t)N_NODES * 4, stream);
    rank_kernel<<<(N_EDGES + 255) / 256, 256, 0, stream>>>(dst, cnt, rank);
    scan_blocks_kernel<<<SCAN_NB, 1024, 0, stream>>>(cnt, excl, partial);
    scan_partial_kernel<<<1, 128, 0, stream>>>(partial);
    scan_add_kernel<<<(N_NODES + 256) / 256, 256, 0, stream>>>(excl, partial, cnt, rowptr, invdeg);
    place2_kernel<<<(N_EDGES + 255) / 256, 256, 0, stream>>>(src, dst, rank, rowptr, cols);
    bounds_kernel<<<2, 160, 0, stream>>>(batch, gstart);

    // ---- input/weight prep ----
    xprep_kernel<<<(N_NODES * 64 + 255) / 256, 256, 0, stream>>>(x, xb);
    wprep_all_kernel<<<(344064 + 255) / 256, 256, 0, stream>>>(
        w1l, w1r, w2l, w2r, w3l, w3r, w1l_b, w1r_b, w2l_b, w2r_b, w3l_b, w3r_b);

    const int MB = (N_NODES + 127) / 128;  // 782

    // ---- layer 1: 50(pad 64) -> 128, leaky_relu; write h1 bf16 + fp8 ----
    aggv_kernel<64><<<(N_NODES * 8 + 255) / 256, 256, 0, stream>>>(xb, rowptr, cols, invdeg, AG);
    glds_gemm<0, 0, 1><<<dim3(1, MB), 256, 0, stream>>>(
        AG, xb, 64, w1l_b, w1r_b, b1, h1, h1_8, N_NODES, 128, nullptr, nullptr);

    // ---- layer 2: 128 -> 256, relu; write h2 bf16 + fp8 ----
    aggv8_kernel<128><<<(N_NODES * 16 + 255) / 256, 256, 0, stream>>>(
        h1_8, rowptr, cols, invdeg, AG);
    glds_gemm<1, 0, 1><<<dim3(2, MB), 256, 0, stream>>>(
        AG, h1, 128, w2l_b, w2r_b, b2, h2, h2_8, N_NODES, 256, nullptr, nullptr);

    // ---- layer 3: 256 -> 512, relu, fused pooled sum ----
    aggv8_kernel<256><<<(N_NODES * 32 + 255) / 256, 256, 0, stream>>>(
        h2_8, rowptr, cols, invdeg, AG);
    hipMemsetAsync(pooled, 0, (size_t)N_GRAPHS * 512 * 4, stream);
    glds_gemm<1, 1, 0><<<dim3(4, MB), 256, 0, stream>>>(
        AG, h2, 256, w3l_b, w3r_b, b3, nullptr, nullptr, N_NODES, 512, batch, pooled);
    pool_finalize<<<N_GRAPHS, 512, 0, stream>>>(pooled, gstart);

    // ---- MLP head ----
    mlp_kernel<1><<<(N_GRAPHS * 256 + 255) / 256, 256, 0, stream>>>(
        pooled, fc1_w, fc1_b, z1, N_GRAPHS, 512, 256);
    mlp_kernel<1><<<(N_GRAPHS * 128 + 255) / 256, 256, 0, stream>>>(
        z1, fc2_w, fc2_b, z2, N_GRAPHS, 256, 128);
    mlp_kernel<0><<<(N_GRAPHS * 15 + 255) / 256, 256, 0, stream>>>(
        z2, cls_w, cls_b, out, N_GRAPHS, 128, 15);
}